// Round 1
// 240.726 us; speedup vs baseline: 1.0512x; 1.0512x over previous
//
#include <hip/hip_runtime.h>
#include <hip/hip_bf16.h>
#include <math.h>

#define Bdim 32
#define Adim 256
#define Ndim 64
#define Gdim 50
#define Fdim 128

typedef __attribute__((ext_vector_type(8)))  short short8;
typedef __attribute__((ext_vector_type(16))) float floatx16;

__device__ __forceinline__ unsigned short f2bf_u(float x) {
    __hip_bfloat16 h = __float2bfloat16(x);
    return __builtin_bit_cast(unsigned short, h);
}
__device__ __forceinline__ unsigned pk2bf(float a, float b) {
    return (unsigned)f2bf_u(a) | ((unsigned)f2bf_u(b) << 16);
}
__device__ __forceinline__ float bf2f(unsigned short v) {
    return __builtin_bit_cast(float, ((unsigned)v) << 16);
}
// shifted softplus, numerically stable
__device__ __forceinline__ float sspf(float v) {
    float t = __expf(-fabsf(v));
    return fmaxf(v, 0.0f) + __logf(1.0f + t) - 0.69314718056f;
}
__device__ __forceinline__ short8 mk8(unsigned a, unsigned b, unsigned c, unsigned d) {
    union { unsigned u[4]; short8 s; } t;
    t.u[0] = a; t.u[1] = b; t.u[2] = c; t.u[3] = d;
    return t.s;
}

// ---------------------------------------------------------------------------
// Kernel 1: y = x @ in2f_w via bf16 MFMA, y in bf16 (unchanged).
// ---------------------------------------------------------------------------
__global__ __launch_bounds__(256) void in2f_mfma2(const float* __restrict__ x,
                                                  const float* __restrict__ w,
                                                  unsigned short* __restrict__ y) {
    __shared__ short sWT[128 * 132];   // w^T[f][i]
    __shared__ short sX [128 * 132];   // x[row][i]
    const int tid = threadIdx.x;

#pragma unroll 4
    for (int k = 0; k < 32; ++k) {
        int idx = tid + k * 256;
        float2 v = *(const float2*)(w + 2 * idx);
        int i = idx >> 6;
        int f = (2 * idx) & 127;
        sWT[f * 132 + i]       = (short)f2bf_u(v.x);
        sWT[(f + 1) * 132 + i] = (short)f2bf_u(v.y);
    }
    const float* xb = x + (size_t)blockIdx.x * (128 * 128);
#pragma unroll 4
    for (int k = 0; k < 32; ++k) {
        int idx = tid + k * 256;
        float2 v = *(const float2*)(xb + 2 * idx);
        int row = idx >> 6;
        int i = (2 * idx) & 127;
        *(unsigned*)&sX[row * 132 + i] = pk2bf(v.x, v.y);
    }
    __syncthreads();

    const int wv = tid >> 6, lane = tid & 63, lm = lane & 31, lh = lane >> 5;
    floatx16 acc[4];
#pragma unroll
    for (int jt = 0; jt < 4; ++jt)
#pragma unroll
        for (int e = 0; e < 16; ++e) acc[jt][e] = 0.0f;

#pragma unroll
    for (int ks = 0; ks < 8; ++ks) {
        int g0 = ks * 16 + lh * 8;
        const short* ap = &sX[(wv * 32 + lm) * 132 + g0];
        uint2 a0 = *(const uint2*)ap;
        uint2 a1 = *(const uint2*)(ap + 4);
        short8 a = mk8(a0.x, a0.y, a1.x, a1.y);
#pragma unroll
        for (int jt = 0; jt < 4; ++jt) {
            const short* bp = &sWT[(jt * 32 + lm) * 132 + g0];
            uint2 b0 = *(const uint2*)bp;
            uint2 b1 = *(const uint2*)(bp + 4);
            acc[jt] = __builtin_amdgcn_mfma_f32_32x32x16_bf16(
                a, mk8(b0.x, b0.y, b1.x, b1.y), acc[jt], 0, 0, 0);
        }
    }
    const int rbase = blockIdx.x * 128 + wv * 32;
#pragma unroll
    for (int jt = 0; jt < 4; ++jt)
#pragma unroll
        for (int r = 0; r < 16; ++r) {
            int row = rbase + (r & 3) + 8 * (r >> 2) + 4 * lh;
            y[(size_t)row * 128 + jt * 32 + lm] = f2bf_u(acc[jt][r]);
        }
}

// ---------------------------------------------------------------------------
// Kernel 2 v4: occupancy-focused rewrite.
//  - f_ij loaded straight into registers as MFMA fragments (no LDS staging,
//    no staging barrier, no 4x redundant re-read). Next super-pair's loads
//    issued right after current conversion -> hidden under dense1/2.
//  - cm/nbr via per-thread broadcast float4/int4 loads + redundant cos
//    (computed AFTER dense2 to keep peak VGPR low).
//  - sFw2 stride 128 + XOR-8short swizzle (2-way free); sRed halved +
//    parity double-buffered -> ONE barrier per iteration.
//  - LDS 52224 B -> 3 blocks/CU (12 waves); grid 1536 x 2-3 sp = 2 exact
//    residency rounds. __launch_bounds__(256,3) pins VGPR <= 170.
// ---------------------------------------------------------------------------
#define SF1 68      // sFw1 stride (shorts): 34 dw -> 2-way free b64
#define NSP 4096    // total super-pairs (B*A/2)
#define GRID2 1536

struct FijRegs { float2 p[13]; };

__device__ __forceinline__ FijRegs load_fij(const float* __restrict__ f_ij,
                                            int sp, int row, int lh) {
    FijRegs F;
    const float* base = f_ij + (size_t)sp * (2 * Ndim * Gdim) + row * Gdim;
#pragma unroll
    for (int ks = 0; ks < 3; ++ks) {
        int g0 = 16 * ks + 8 * lh;
#pragma unroll
        for (int j = 0; j < 4; ++j)
            F.p[ks * 4 + j] = *(const float2*)(base + g0 + 2 * j);
    }
    F.p[12] = *(const float2*)(base + 48);   // both lh halves: g=48,49
    return F;
}

__device__ __forceinline__ void cf_body(
    int sp, int par, const FijRegs& F, int nsp, FijRegs& Fn,
    const float* __restrict__ f_ij, const float* __restrict__ r_ij,
    const float* __restrict__ mask, const int* __restrict__ nbr,
    const unsigned short* __restrict__ ybf, float* __restrict__ out,
    float4 fb2v, const short* sFw1, const short* sFw2,
    float (*sRed)[2][128], int wv, int lm, int lh, int row)
{
    // ---- convert this iteration's f_ij fragments (bf16, MFMA layout) ----
    short8 bfr[4];
#pragma unroll
    for (int ks = 0; ks < 3; ++ks)
        bfr[ks] = mk8(pk2bf(F.p[ks*4+0].x, F.p[ks*4+0].y),
                      pk2bf(F.p[ks*4+1].x, F.p[ks*4+1].y),
                      pk2bf(F.p[ks*4+2].x, F.p[ks*4+2].y),
                      pk2bf(F.p[ks*4+3].x, F.p[ks*4+3].y));
    {
        // ks=3: lh=0 holds g=48,49, bias 1.0 at g=50, zeros; lh=1 all zero
        unsigned u0 = lh ? 0u : pk2bf(F.p[12].x, F.p[12].y);
        unsigned u1 = lh ? 0u : 0x00003F80u;
        bfr[3] = mk8(u0, u1, 0u, 0u);
    }
    // ---- prefetch next super-pair's f_ij (lands during dense1/2) ----
    if (nsp >= 0) Fn = load_fij(f_ij, nsp, row, lh);

    // ---- dense1: A = fw1T (LDS), B = f_ij (regs); ssp; remap to A2 ----
    unsigned A2[8][4];
#pragma unroll
    for (int ft = 0; ft < 4; ++ft) {
        floatx16 a1;
#pragma unroll
        for (int e = 0; e < 16; ++e) a1[e] = 0.0f;
#pragma unroll
        for (int ks = 0; ks < 4; ++ks) {
            const short* ap = &sFw1[(ft * 32 + lm) * SF1 + ks * 16 + lh * 8];
            uint2 a0 = *(const uint2*)ap;
            uint2 a1v = *(const uint2*)(ap + 4);
            a1 = __builtin_amdgcn_mfma_f32_32x32x16_bf16(
                mk8(a0.x, a0.y, a1v.x, a1v.y), bfr[ks], a1, 0, 0, 0);
        }
        unsigned P[8], X[8];
#pragma unroll
        for (int q = 0; q < 8; ++q)
            P[q] = pk2bf(sspf(a1[2 * q]), sspf(a1[2 * q + 1]));
#pragma unroll
        for (int q = 0; q < 8; ++q) X[q] = (unsigned)__shfl_xor((int)P[q], 32);
        A2[2*ft][0]   = lh ? X[2] : P[0];  A2[2*ft][1]   = lh ? X[3] : P[1];
        A2[2*ft][2]   = lh ? P[2] : X[0];  A2[2*ft][3]   = lh ? P[3] : X[1];
        A2[2*ft+1][0] = lh ? X[6] : P[4];  A2[2*ft+1][1] = lh ? X[7] : P[5];
        A2[2*ft+1][2] = lh ? P[6] : X[4];  A2[2*ft+1][3] = lh ? P[7] : X[5];
    }

    // ---- dense2: A = W1 (regs), B = fw2T (LDS, XOR-swizzled) ----
    floatx16 acc2[4];
#pragma unroll
    for (int jt = 0; jt < 4; ++jt)
#pragma unroll
        for (int e = 0; e < 16; ++e) acc2[jt][e] = 0.0f;
#pragma unroll
    for (int ks = 0; ks < 8; ++ks) {
        short8 a = mk8(A2[ks][0], A2[ks][1], A2[ks][2], A2[ks][3]);
#pragma unroll
        for (int jt = 0; jt < 4; ++jt) {
            int rw = jt * 32 + lm;
            const short* bp = &sFw2[rw * 128 + ((ks * 16 + lh * 8) ^ ((rw & 15) << 3))];
            uint2 b0 = *(const uint2*)bp;
            uint2 b1 = *(const uint2*)(bp + 4);
            acc2[jt] = __builtin_amdgcn_mfma_f32_32x32x16_bf16(
                a, mk8(b0.x, b0.y, b1.x, b1.y), acc2[jt], 0, 0, 0);
        }
    }

    // ---- cutoff*mask + neighbor indices: broadcast loads, in-reg cos ----
    const int site = sp * 2 + (wv >> 1);
    float cmv[16]; int nbv[16];
#pragma unroll
    for (int rq = 0; rq < 4; ++rq) {
        int off = site * Ndim + (wv & 1) * 32 + rq * 8 + lh * 4;
        float4 r4 = *(const float4*)(r_ij + off);
        float4 m4 = *(const float4*)(mask + off);
        int4   n4 = *(const int4*)(nbr + off);
        float rr[4] = { r4.x, r4.y, r4.z, r4.w };
        float mm[4] = { m4.x, m4.y, m4.z, m4.w };
        int   nn[4] = { n4.x, n4.y, n4.z, n4.w };
#pragma unroll
        for (int j = 0; j < 4; ++j) {
            float c = 0.5f * (__cosf(rr[j] * 0.62831853071796f) + 1.0f);
            c = (rr[j] < 5.0f) ? c : 0.0f;
            cmv[rq * 4 + j] = c * mm[j];
            nbv[rq * 4 + j] = nn[j];
        }
    }

    // ---- epilogue: out[f] += cm[n]*(W2[n,f]+fb2[f])*y[nbr[n],f] ----
    const int bofs = (site >> 8) * Adim;
    float part[4] = {0.f, 0.f, 0.f, 0.f};
#pragma unroll
    for (int r = 0; r < 16; ++r) {
        float cm = cmv[r];
        const unsigned short* yr = ybf + (size_t)(bofs + nbv[r]) * Fdim;
#pragma unroll
        for (int jt = 0; jt < 4; ++jt) {
            float fb2j = (jt == 0) ? fb2v.x : (jt == 1) ? fb2v.y
                       : (jt == 2) ? fb2v.z : fb2v.w;
            float yv = bf2f(yr[jt * 32 + lm]);
            part[jt] += (acc2[jt][r] + fb2j) * cm * yv;
        }
    }
#pragma unroll
    for (int jt = 0; jt < 4; ++jt) part[jt] += __shfl_xor(part[jt], 32);

    const int s = wv >> 1;
    if (wv & 1) {
#pragma unroll
        for (int k = 0; k < 2; ++k)
            sRed[par][s][(2 * lh + k) * 32 + lm] = part[2 * lh + k];
    }
    __syncthreads();   // only barrier per iteration (sRed parity-dbuf'd)
    if (!(wv & 1)) {
#pragma unroll
        for (int k = 0; k < 2; ++k) {
            int jt = 2 * lh + k;
            int f = jt * 32 + lm;
            out[(size_t)site * Fdim + f] = part[jt] + sRed[par][s][f];
        }
    }
}

__global__ __launch_bounds__(256, 3) void cfconv_mfma4(
    const float* __restrict__ r_ij, const float* __restrict__ f_ij,
    const float* __restrict__ mask, const int* __restrict__ nbr,
    const float* __restrict__ fw1, const float* __restrict__ fb1,
    const float* __restrict__ fw2, const float* __restrict__ fb2,
    const unsigned short* __restrict__ ybf, float* __restrict__ out)
{
    __shared__ short sFw1[128 * SF1];       // 17408 B: fw1T[f][g], bias @ g=50
    __shared__ short sFw2[128 * 128];       // 32768 B: fw2T[f][h], XOR-swizzled
    __shared__ float sRed[2][2][128];       //  2048 B: parity x site x f
    // total 52224 B -> 3 blocks/CU

    const int tid = threadIdx.x, wv = tid >> 6, lane = tid & 63;
    const int lm = lane & 31, lh = lane >> 5;
    const int bid = blockIdx.x;
    const int row = wv * 32 + lm;

    FijRegs FA = load_fij(f_ij, bid, row, lh);   // issue before staging

    // stage fw1T (+ bias col g=50, zeros g=51..63)
    for (int idx = tid; idx < Gdim * 128; idx += 256) {
        int g = idx >> 7, f = idx & 127;
        sFw1[f * SF1 + g] = (short)f2bf_u(fw1[idx]);
    }
    for (int idx = tid; idx < 128 * 14; idx += 256) {
        int f = idx / 14, g = Gdim + idx % 14;
        sFw1[f * SF1 + g] = (g == Gdim) ? (short)f2bf_u(fb1[f]) : (short)0;
    }
    // stage fw2T swizzled: group(h) ^= (f&15)
    for (int idx = tid; idx < 128 * 128; idx += 256) {
        int h = idx >> 7, f = idx & 127;
        sFw2[f * 128 + (h ^ ((f & 15) << 3))] = (short)f2bf_u(fw2[idx]);
    }
    float4 fb2v;
    fb2v.x = fb2[lm]; fb2v.y = fb2[32 + lm]; fb2v.z = fb2[64 + lm]; fb2v.w = fb2[96 + lm];
    __syncthreads();

    const int sp1 = bid + GRID2, sp2 = bid + 2 * GRID2;
    FijRegs FB;
    cf_body(bid, 0, FA, sp1, FB, f_ij, r_ij, mask, nbr, ybf, out,
            fb2v, sFw1, sFw2, sRed, wv, lm, lh, row);
    cf_body(sp1, 1, FB, (sp2 < NSP) ? sp2 : -1, FA, f_ij, r_ij, mask, nbr, ybf, out,
            fb2v, sFw1, sFw2, sRed, wv, lm, lh, row);
    if (sp2 < NSP)
        cf_body(sp2, 0, FA, -1, FB, f_ij, r_ij, mask, nbr, ybf, out,
                fb2v, sFw1, sFw2, sRed, wv, lm, lh, row);
}

// ---------------------------------------------------------------------------
extern "C" void kernel_launch(void* const* d_in, const int* in_sizes, int n_in,
                              void* d_out, int out_size, void* d_ws, size_t ws_size,
                              hipStream_t stream) {
    const float* x      = (const float*)d_in[0];
    const float* r_ij   = (const float*)d_in[1];
    const float* f_ij   = (const float*)d_in[2];
    const float* mask   = (const float*)d_in[3];
    const int*   nbr    = (const int*)d_in[4];
    const float* in2f_w = (const float*)d_in[5];
    const float* fw1    = (const float*)d_in[6];
    const float* fb1    = (const float*)d_in[7];
    const float* fw2    = (const float*)d_in[8];
    const float* fb2    = (const float*)d_in[9];
    float* out = (float*)d_out;
    unsigned short* y = (unsigned short*)d_ws;   // (B*A, F) bf16 = 2 MB scratch

    in2f_mfma2<<<64, 256, 0, stream>>>(x, in2f_w, y);
    cfconv_mfma4<<<GRID2, 256, 0, stream>>>(r_ij, f_ij, mask, nbr,
                                            fw1, fb1, fw2, fb2, y, out);
}